// Round 4
// baseline (392.298 us; speedup 1.0000x reference)
//
#include <hip/hip_runtime.h>
#include <hip/hip_bf16.h>
#include <math.h>

#define NUMS 100
#define SUMS 199
#define BATCH 4096

typedef __attribute__((ext_vector_type(8))) short short8;   // 8 bf16 (4 VGPRs)
typedef __attribute__((ext_vector_type(4))) float float4v;  // MFMA accumulator

union Frag8 { short8 v; unsigned u[4]; };

static __device__ inline unsigned pk_bf16(float a, float b) {
    __hip_bfloat162 h = __float22bfloat162_rn(make_float2(a, b));
    union { __hip_bfloat162 h; unsigned u; } c; c.h = h; return c.u;
}
static __device__ inline unsigned short f2bf(float a) {
    union { __hip_bfloat16 h; unsigned short u; } c; c.h = __float2bfloat16(a); return c.u;
}

// LDS layout (20800 B total -> 7 blocks/CU):
//  [0,6336)      img bf16: 4 images x 396 dwords (792 shorts, 784 used)
//                -- after conv2, per-image overlay: p2[4][256] fp32 (1024B < 1584B)
//  [6336,13376)  p1 copy0: 4 x 880 shorts  -- after conv2 barrier, fc overlay
//  [13376,20416) p1 copy1 (elem i at slot i+1): 4 x 880 shorts
//  [20416,20800) ko2 table: 96 ints (conv2 k-pair -> p1 element offset)
__global__ __launch_bounds__(256) void lenet_circuit_kernel(
    const float* __restrict__ images,
    const float* __restrict__ c1w, const float* __restrict__ c1b,
    const float* __restrict__ c2w, const float* __restrict__ c2b,
    const float* __restrict__ f1w, const float* __restrict__ f1b,
    const float* __restrict__ f2w, const float* __restrict__ f2b,
    const float* __restrict__ f3w, const float* __restrict__ f3b,
    float* __restrict__ out)
{
    __shared__ __align__(16) unsigned char s_mem[20800];

    unsigned*       imgu  = (unsigned*)s_mem;                  // [4][396]
    unsigned short* p1a   = (unsigned short*)(s_mem + 6336);   // [4][880]
    unsigned short* p1b   = (unsigned short*)(s_mem + 13376);  // [4][880]
    const unsigned* p1au  = (const unsigned*)(s_mem + 6336);   // [4][440]
    const unsigned* p1bu  = (const unsigned*)(s_mem + 13376);
    int*            ko2   = (int*)(s_mem + 20416);             // [96]

    const int t = threadIdx.x;
    const int bid = blockIdx.x;
    const int lane = t & 63;
    const int wav  = t >> 6;        // image index within batch element
    const int c    = lane & 15;
    const int h    = lane >> 4;

    // ---- staging: images fp32->bf16 packed; ko2 table; zero p1 pads ----
    {
        const float4* g = (const float4*)(images + (size_t)bid * 3136);
        for (int i = t; i < 784; i += 256) {
            const float4 v = g[i];
            const int im = i / 196, j = i % 196;
            imgu[im * 396 + 2 * j]     = pk_bf16(v.x, v.y);
            imgu[im * 396 + 2 * j + 1] = pk_bf16(v.z, v.w);
        }
        if (t < 96) {
            int off = 0;
            if (t < 90) { const int ic = t / 15, r = t % 15; off = ic * 144 + (r / 3) * 12 + 2 * (r % 3); }
            ko2[t] = off;
        } else if (t < 160) {
            const int idx = t - 96;
            p1a[(idx >> 4) * 880 + 864 + (idx & 15)] = 0;
        } else if (t < 224) {
            const int idx = t - 160;
            p1b[(idx >> 4) * 880 + 864 + (idx & 15)] = 0;
        } else if (t < 228) {
            p1b[(t - 224) * 880] = 0;
        }
    }

    // ---- A-fragment conv1: rows 0-5 = weights, rows 8-13 = weights shifted +1 in x ----
    // K order: pair p = h*4 + j/2 (p<15): ky = p/3, kx = 2*(p%3) + (j&1); kx in 0..5 (col 5 zero-wt)
    Frag8 a1;
    {
        float v[8];
        #pragma unroll
        for (int j = 0; j < 8; ++j) {
            const int p = h * 4 + (j >> 1), bb = j & 1;
            float w = 0.f;
            if (p < 15) {
                const int ky = p / 3, kx = 2 * (p % 3) + bb;
                if (c < 6) { if (kx < 5) w = c1w[c * 25 + ky * 5 + kx]; }
                else if (c >= 8 && c < 14) { if (kx >= 1) w = c1w[(c - 8) * 25 + ky * 5 + (kx - 1)]; }
            }
            v[j] = w;
        }
        #pragma unroll
        for (int q = 0; q < 4; ++q) a1.u[q] = pk_bf16(v[2 * q], v[2 * q + 1]);
    }
    // ---- A-fragments conv2: K=192, pair p' = s*16+h*4+j/2; p'<90: ic=p'/15, ky=(p'%15)/3, kx=2*(p'%15%3)+(j&1) ----
    Frag8 a2[6];
    #pragma unroll
    for (int s = 0; s < 6; ++s) {
        float v[8];
        #pragma unroll
        for (int j = 0; j < 8; ++j) {
            const int p = s * 16 + h * 4 + (j >> 1), bb = j & 1;
            float w = 0.f;
            if (p < 90) {
                const int ic = p / 15, r = p % 15, ky = r / 3, kx = 2 * (r % 3) + bb;
                if (kx < 5) w = c2w[c * 150 + ic * 25 + ky * 5 + kx];
            }
            v[j] = w;
        }
        #pragma unroll
        for (int q = 0; q < 4; ++q) a2[s].u[q] = pk_bf16(v[2 * q], v[2 * q + 1]);
    }
    __syncthreads();

    // ---- conv1 (MFMA, dual x-shift): 18 MFMAs, n=(b1=y-lsb, x2=(c>>1)&3, yb=(c>>3)&1) ----
    {
        const int yb1 = c & 1, x2 = (c >> 1) & 3, yb = (c >> 3) & 1;
        int ko1[4];
        #pragma unroll
        for (int q = 0; q < 4; ++q) {
            const int p = h * 4 + q;
            ko1[q] = (p < 15) ? (p / 3) * 28 + 2 * (p % 3) : 0;
        }
        const unsigned* im0 = imgu + wav * 396;
        unsigned short* w0 = p1a + wav * 880;
        unsigned short* w1 = p1b + wav * 880;

        for (int qyt = 0; qyt < 6; ++qyt) {
            const int py = 4 * qyt + 2 * yb + yb1;
            #pragma unroll
            for (int qxt = 0; qxt < 3; ++qxt) {
                const int x0 = 8 * qxt + 2 * x2;
                const int eb = py * 28 + x0;       // always even
                Frag8 bf;
                #pragma unroll
                for (int q = 0; q < 4; ++q) bf.u[q] = im0[(eb + ko1[q]) >> 1];
                float4v acc = {0.f, 0.f, 0.f, 0.f};
                acc = __builtin_amdgcn_mfma_f32_16x16x32_bf16(a1.v, bf.v, acc, 0, 0, 0);
                #pragma unroll
                for (int r = 0; r < 4; ++r) {
                    float x = acc[r];
                    x = fmaxf(x, __shfl_xor(x, 32));   // x-pair (row oc <-> oc+8)
                    x = fmaxf(x, __shfl_xor(x, 1));    // y-pair
                    const int oc = h * 4 + r;
                    if (h < 2 && yb1 == 0 && oc < 6) {
                        const int qy = 2 * qyt + yb, qx = 4 * qxt + x2;
                        const unsigned short bv = f2bf(fmaxf(x + c1b[oc], 0.f));
                        const int elem = oc * 144 + qy * 12 + qx;
                        w0[elem] = bv;
                        w1[elem + 1] = bv;
                    }
                }
            }
        }
    }
    // no barrier: this wave's conv2 reads only this wave's p1

    // ---- conv2 (MFMA): 24 MFMAs, n: px=c&7, py=(c>>3)+2nt ----
    {
        float4v acc[4];
        #pragma unroll
        for (int nt = 0; nt < 4; ++nt) acc[nt] = (float4v){0.f, 0.f, 0.f, 0.f};

        const int px = c & 7, pxo = px & 1;
        const unsigned* arr = (pxo ? p1bu : p1au) + wav * 440;

        for (int s = 0; s < 6; ++s) {
            int off[4];
            #pragma unroll
            for (int q = 0; q < 4; ++q) off[q] = ko2[s * 16 + h * 4 + q];
            #pragma unroll
            for (int nt = 0; nt < 4; ++nt) {
                const int eb = ((c >> 3) + 2 * nt) * 12 + px;
                Frag8 bf;
                #pragma unroll
                for (int q = 0; q < 4; ++q) bf.u[q] = arr[((eb + off[q]) >> 1) + pxo];
                acc[nt] = __builtin_amdgcn_mfma_f32_16x16x32_bf16(a2[s].v, bf.v, acc[nt], 0, 0, 0);
            }
        }
        float* p2 = (float*)(s_mem + wav * 1584);
        #pragma unroll
        for (int nt = 0; nt < 4; ++nt) {
            #pragma unroll
            for (int r = 0; r < 4; ++r) {
                float x = acc[nt][r];
                x = fmaxf(x, __shfl_xor(x, 1));   // px pair
                x = fmaxf(x, __shfl_xor(x, 8));   // py pair
                if ((c & 9) == 0) {
                    const int oc = h * 4 + r, qx = c >> 1;
                    p2[oc * 16 + nt * 4 + qx] = fmaxf(x + c2b[oc], 0.f);
                }
            }
        }
    }
    __syncthreads();

    // fc overlays in p1 region (dead after barrier)
    float* s_f1 = (float*)(s_mem + 6336);           // [4][120]
    float* s_f2 = (float*)(s_mem + 6336 + 1920);    // [4][84]
    float* s_lg = (float*)(s_mem + 6336 + 3264);    // [4][10]
    float* s_l1 = (float*)(s_mem + 6336 + 3424);    // [100]
    float* s_l2 = (float*)(s_mem + 6336 + 3824);    // [100]

    // ---- fc1 (256->120)+relu: weights read once per image pair ----
    if (t < 240) {
        const int o = t % 120;
        const int im0 = (t / 120) * 2, im1 = im0 + 1;
        const float4* wr = (const float4*)(f1w + (size_t)o * 256);
        const float4* x0 = (const float4*)(s_mem + im0 * 1584);
        const float4* x1 = (const float4*)(s_mem + im1 * 1584);
        float a0 = f1b[o], a1v = a0;
        #pragma unroll 8
        for (int k = 0; k < 64; ++k) {
            const float4 w4 = wr[k], p = x0[k], q = x1[k];
            a0  += w4.x * p.x + w4.y * p.y + w4.z * p.z + w4.w * p.w;
            a1v += w4.x * q.x + w4.y * q.y + w4.z * q.z + w4.w * q.w;
        }
        s_f1[im0 * 120 + o] = fmaxf(a0, 0.f);
        s_f1[im1 * 120 + o] = fmaxf(a1v, 0.f);
    }
    __syncthreads();

    // ---- fc2 (120->84)+relu ----
    if (t < 168) {
        const int o = t % 84;
        const int im0 = (t / 84) * 2, im1 = im0 + 1;
        const float4* wr = (const float4*)(f2w + (size_t)o * 120);
        const float4* x0 = (const float4*)(s_f1 + im0 * 120);
        const float4* x1 = (const float4*)(s_f1 + im1 * 120);
        float a0 = f2b[o], a1v = a0;
        #pragma unroll 6
        for (int k = 0; k < 30; ++k) {
            const float4 w4 = wr[k], p = x0[k], q = x1[k];
            a0  += w4.x * p.x + w4.y * p.y + w4.z * p.z + w4.w * p.w;
            a1v += w4.x * q.x + w4.y * q.y + w4.z * q.z + w4.w * q.w;
        }
        s_f2[im0 * 84 + o] = fmaxf(a0, 0.f);
        s_f2[im1 * 84 + o] = fmaxf(a1v, 0.f);
    }
    __syncthreads();

    // ---- fc3 (84->10) ----
    if (t < 40) {
        const int o = t % 10;
        const int im = t / 10;
        const float4* wr = (const float4*)(f3w + (size_t)o * 84);
        const float4* xr = (const float4*)(s_f2 + im * 84);
        float a = f3b[o];
        #pragma unroll
        for (int k = 0; k < 21; ++k) {
            const float4 w4 = wr[k], p = xr[k];
            a += w4.x * p.x + w4.y * p.y + w4.z * p.z + w4.w * p.w;
        }
        s_lg[im * 10 + o] = a;
    }
    __syncthreads();

    // ---- log_softmax per image ----
    if (t < 4) {
        float mx = -INFINITY;
        #pragma unroll
        for (int i = 0; i < 10; ++i) mx = fmaxf(mx, s_lg[t * 10 + i]);
        float sum = 0.f;
        #pragma unroll
        for (int i = 0; i < 10; ++i) sum += expf(s_lg[t * 10 + i] - mx);
        const float lse = mx + logf(sum);
        #pragma unroll
        for (int i = 0; i < 10; ++i) s_lg[t * 10 + i] -= lse;
    }
    __syncthreads();

    // ---- circuit: per-number log-probs ----
    if (t < NUMS) {
        s_l1[t] = s_lg[0 * 10 + t / 10] + s_lg[1 * 10 + t % 10];
    } else if (t < 2 * NUMS) {
        const int k = t - NUMS;
        s_l2[k] = s_lg[2 * 10 + k / 10] + s_lg[3 * 10 + k % 10];
    }
    __syncthreads();

    // ---- per-segment exact logsumexp ----
    if (t < SUMS) {
        const int s   = t;
        const int ilo = (s > 99) ? (s - 99) : 0;
        const int ihi = (s < 99) ? s : 99;
        float m = -INFINITY;
        for (int i = ilo; i <= ihi; ++i) m = fmaxf(m, s_l1[i] + s_l2[s - i]);
        float sum = 0.f;
        for (int i = ilo; i <= ihi; ++i) sum += expf(s_l1[i] + s_l2[s - i] - m);
        out[(size_t)bid * SUMS + s] = logf(sum) + m;
    }
}

extern "C" void kernel_launch(void* const* d_in, const int* in_sizes, int n_in,
                              void* d_out, int out_size, void* d_ws, size_t ws_size,
                              hipStream_t stream) {
    const float* images = (const float*)d_in[0];
    const float* c1w = (const float*)d_in[1];
    const float* c1b = (const float*)d_in[2];
    const float* c2w = (const float*)d_in[3];
    const float* c2b = (const float*)d_in[4];
    const float* f1w = (const float*)d_in[5];
    const float* f1b = (const float*)d_in[6];
    const float* f2w = (const float*)d_in[7];
    const float* f2b = (const float*)d_in[8];
    const float* f3w = (const float*)d_in[9];
    const float* f3b = (const float*)d_in[10];
    float* out = (float*)d_out;

    lenet_circuit_kernel<<<BATCH, 256, 0, stream>>>(
        images, c1w, c1b, c2w, c2b, f1w, f1b, f2w, f2b, f3w, f3b, out);
}

// Round 6
// 259.290 us; speedup vs baseline: 1.5130x; 1.5130x over previous
//
#include <hip/hip_runtime.h>
#include <hip/hip_bf16.h>
#include <math.h>

#define NUMS 100
#define SUMS 199
#define NBLK 2048   // 8 images = 2 batch elements per block

typedef __attribute__((ext_vector_type(8))) short short8;   // 8 bf16
typedef __attribute__((ext_vector_type(4))) float float4v;  // MFMA acc

union Frag8 { short8 v; unsigned u[4]; uint4 q; };

static __device__ inline unsigned pk_bf16(float a, float b) {
    __hip_bfloat162 h = __float22bfloat162_rn(make_float2(a, b));
    union { __hip_bfloat162 h; unsigned u; } c; c.h = h; return c.u;
}
static __device__ inline unsigned short f2bf(float a) {
    union { __hip_bfloat16 h; unsigned short u; } c; c.h = __float2bfloat16(a); return c.u;
}

// LDS (31264 B -> 5 blocks/CU):
//  region A [0,12576): images bf16 [8][393 dwords]; after conv1 reused for
//    p2f[8][260] fp32, f1f[8][124], then f2f[8][88], lgf[8][12], l1f/l2f[2][100]
//  p1 [12576,31264): conv1 out bf16 [8 img][12 y][12 x][8 ic-pad] + 256B tail.
//  p1 is FULLY ZEROED at staging: conv2's uint4 A-loads cover ic-pad shorts
//  6-7 and ky/kx wrap cells with zero weights; stale Inf/NaN there would give
//  0*Inf=NaN which relu's fmaxf(NaN,0)=0 silently launders (the R5 bug).
__global__ __launch_bounds__(256) void lenet_circuit_kernel(
    const float* __restrict__ images,
    const float* __restrict__ c1w, const float* __restrict__ c1b,
    const float* __restrict__ c2w, const float* __restrict__ c2b,
    const float* __restrict__ f1w, const float* __restrict__ f1b,
    const float* __restrict__ f2w, const float* __restrict__ f2b,
    const float* __restrict__ f3w, const float* __restrict__ f3b,
    float* __restrict__ out)
{
    __shared__ __align__(16) unsigned char s_mem[31264];
    unsigned*       imgu = (unsigned*)s_mem;                       // [8][393]
    unsigned short* p1s  = (unsigned short*)(s_mem + 12576);       // [8][1152]
    const uint4*    p1u4 = (const uint4*)(s_mem + 12576);
    float*          Af   = (float*)s_mem;

    float* p2f = Af;            // [8][260]
    float* f1f = Af + 2080;     // [8][124]
    float* f2f = Af;            // [8][88]
    float* lgf = Af + 704;      // [8][12]
    float* l1f = Af + 800;      // [2][100]
    float* l2f = Af + 1000;     // [2][100]

    const int t = threadIdx.x, bid = blockIdx.x;
    const int lane = t & 63, wav = t >> 6;
    const int c = lane & 15, h = lane >> 4;

    // ---- zero the whole p1 region (pads included) ----
    {
        uint4* pz = (uint4*)(s_mem + 12576);
        const uint4 z = {0u, 0u, 0u, 0u};
        for (int i = t; i < 1168; i += 256) pz[i] = z;
    }

    // ---- stage 8 images fp32 -> bf16 packed ----
    {
        const float4* g = (const float4*)(images + (size_t)bid * 6272);
        for (int i = t; i < 1568; i += 256) {
            const float4 v = g[i];
            const int im = i / 196, j = i % 196;
            imgu[im * 393 + 2 * j]     = pk_bf16(v.x, v.y);
            imgu[im * 393 + 2 * j + 1] = pk_bf16(v.z, v.w);
        }
    }

    // ---- conv1 weights (A-side, dual x-shift): rows 0-5 = w, rows 8-13 = w shifted +1 ----
    Frag8 a1;
    {
        float v[8];
        #pragma unroll
        for (int j = 0; j < 8; ++j) {
            const int p = h * 4 + (j >> 1), bb = j & 1;
            float w = 0.f;
            if (p < 15) {
                const int ky = p / 3, kx = 2 * (p % 3) + bb;
                if (c < 6) { if (kx < 5) w = c1w[c * 25 + ky * 5 + kx]; }
                else if (c >= 8 && c < 14) { if (kx >= 1) w = c1w[(c - 8) * 25 + ky * 5 + (kx - 1)]; }
            }
            v[j] = w;
        }
        #pragma unroll
        for (int q = 0; q < 4; ++q) a1.u[q] = pk_bf16(v[2 * q], v[2 * q + 1]);
    }

    // ---- conv2 weights (B-side): lane n=c=oc holds k=32s+8h+j; K order (ky,kx6,ic8) ----
    Frag8 w2[8];
    #pragma unroll
    for (int s = 0; s < 8; ++s) {
        float v[8];
        #pragma unroll
        for (int j = 0; j < 8; ++j) {
            const int k = 32 * s + 8 * h + j, D = k >> 1;
            const int ky = D / 24, rem = D % 24, kx = rem >> 2, ic = 2 * (rem & 3) + (j & 1);
            v[j] = (ky < 5 && kx < 5 && ic < 6) ? c2w[c * 150 + ic * 25 + ky * 5 + kx] : 0.f;
        }
        #pragma unroll
        for (int q = 0; q < 4; ++q) w2[s].u[q] = pk_bf16(v[2 * q], v[2 * q + 1]);
    }
    int koff[8];   // conv2 A-read offset per K-block, uint4 units
    #pragma unroll
    for (int s = 0; s < 8; ++s) {
        const int D0 = 16 * s + 4 * h;
        koff[s] = (D0 / 24) * 12 + ((D0 % 24) >> 2);
    }
    float biasv[4];
    #pragma unroll
    for (int r = 0; r < 4; ++r) {
        const int oc = 4 * h + r;
        biasv[r] = (h < 2 && oc < 6) ? c1b[oc] : 0.f;
    }
    __syncthreads();

    // ---- conv1: 1 MFMA per pool-quad; cols n = (y-lsb, img), rows = (oc, x-shift) ----
    {
        int pd[4];
        #pragma unroll
        for (int q = 0; q < 4; ++q) {
            const int p = 4 * h + q;
            pd[q] = (p < 15) ? (p / 3) * 14 + (p % 3) : 0;
        }
        const int n = c, img = n >> 1;
        const int imb = img * 393 + (n & 1) * 14;
        for (int qy = wav * 3; qy < wav * 3 + 3; ++qy) {
            #pragma unroll
            for (int qx = 0; qx < 12; ++qx) {
                const int base = imb + qy * 28 + qx;
                Frag8 bf;
                #pragma unroll
                for (int q = 0; q < 4; ++q) bf.u[q] = imgu[base + pd[q]];
                float4v acc = {0.f, 0.f, 0.f, 0.f};
                acc = __builtin_amdgcn_mfma_f32_16x16x32_bf16(a1.v, bf.v, acc, 0, 0, 0);
                #pragma unroll
                for (int r = 0; r < 4; ++r) {
                    float v = acc[r];
                    v = fmaxf(v, __shfl_xor(v, 1));    // y partner (col bit0)
                    v = fmaxf(v, __shfl_xor(v, 32));   // x partner (row +8 = shifted w)
                    const int oc = 4 * h + r;
                    if (h < 2 && (n & 1) == 0 && oc < 6)
                        p1s[img * 1152 + qy * 96 + qx * 8 + oc] =
                            f2bf(fmaxf(v + biasv[r], 0.f));
                }
            }
        }
    }
    __syncthreads();

    // ---- conv2: A = patches (1 ds_read_b128/MFMA), B = weights in regs; in-lane pooling ----
    {
        const int pxl = (c & 1) + 2 * ((c >> 2) & 1);
        const int pyl = ((c >> 1) & 1) + 2 * ((c >> 3) & 1);
        const float b2v = c2b[c];
        #pragma unroll
        for (int ii = 0; ii < 2; ++ii) {
            const int i0 = 2 * wav + ii;
            #pragma unroll
            for (int mt = 0; mt < 4; ++mt) {
                const int px = pxl + 4 * (mt & 1), py = pyl + 4 * (mt >> 1);
                const int base = i0 * 144 + py * 12 + px;
                float4v acc = {0.f, 0.f, 0.f, 0.f};
                #pragma unroll
                for (int s = 0; s < 8; ++s) {
                    Frag8 af; af.q = p1u4[base + koff[s]];
                    acc = __builtin_amdgcn_mfma_f32_16x16x32_bf16(af.v, w2[s].v, acc, 0, 0, 0);
                }
                const float p = fmaxf(fmaxf(acc[0], acc[1]), fmaxf(acc[2], acc[3]));
                const int qx = (h & 1) + 2 * (mt & 1), qy = (h >> 1) + 2 * (mt >> 1);
                p2f[i0 * 260 + c * 16 + qy * 4 + qx] = fmaxf(p + b2v, 0.f);
            }
        }
    }
    __syncthreads();

    // ---- fc1 (256->120)+relu: thread = (o, 4-img group), 1 pass, 4-way ILP ----
    if (t < 240) {
        const int o = t >> 1, q = t & 1;
        const float4* wr = (const float4*)(f1w + (size_t)o * 256);
        const float* x0 = p2f + (4 * q) * 260;
        float a0 = f1b[o], a1v = a0, a2 = a0, a3 = a0;
        #pragma unroll 2
        for (int k = 0; k < 64; ++k) {
            const float4 w4 = wr[k];
            const float4 xa = ((const float4*)x0)[k];
            const float4 xb = ((const float4*)(x0 + 260))[k];
            const float4 xc = ((const float4*)(x0 + 520))[k];
            const float4 xd = ((const float4*)(x0 + 780))[k];
            a0  += w4.x * xa.x + w4.y * xa.y + w4.z * xa.z + w4.w * xa.w;
            a1v += w4.x * xb.x + w4.y * xb.y + w4.z * xb.z + w4.w * xb.w;
            a2  += w4.x * xc.x + w4.y * xc.y + w4.z * xc.z + w4.w * xc.w;
            a3  += w4.x * xd.x + w4.y * xd.y + w4.z * xd.z + w4.w * xd.w;
        }
        f1f[(4 * q + 0) * 124 + o] = fmaxf(a0, 0.f);
        f1f[(4 * q + 1) * 124 + o] = fmaxf(a1v, 0.f);
        f1f[(4 * q + 2) * 124 + o] = fmaxf(a2, 0.f);
        f1f[(4 * q + 3) * 124 + o] = fmaxf(a3, 0.f);
    }
    __syncthreads();

    // ---- fc2 (120->84)+relu ----
    if (t < 168) {
        const int o = t >> 1, q = t & 1;
        const float4* wr = (const float4*)(f2w + (size_t)o * 120);
        const float* x0 = f1f + (4 * q) * 124;
        float a0 = f2b[o], a1v = a0, a2 = a0, a3 = a0;
        #pragma unroll 2
        for (int k = 0; k < 30; ++k) {
            const float4 w4 = wr[k];
            const float4 xa = ((const float4*)x0)[k];
            const float4 xb = ((const float4*)(x0 + 124))[k];
            const float4 xc = ((const float4*)(x0 + 248))[k];
            const float4 xd = ((const float4*)(x0 + 372))[k];
            a0  += w4.x * xa.x + w4.y * xa.y + w4.z * xa.z + w4.w * xa.w;
            a1v += w4.x * xb.x + w4.y * xb.y + w4.z * xb.z + w4.w * xb.w;
            a2  += w4.x * xc.x + w4.y * xc.y + w4.z * xc.z + w4.w * xc.w;
            a3  += w4.x * xd.x + w4.y * xd.y + w4.z * xd.z + w4.w * xd.w;
        }
        f2f[(4 * q + 0) * 88 + o] = fmaxf(a0, 0.f);
        f2f[(4 * q + 1) * 88 + o] = fmaxf(a1v, 0.f);
        f2f[(4 * q + 2) * 88 + o] = fmaxf(a2, 0.f);
        f2f[(4 * q + 3) * 88 + o] = fmaxf(a3, 0.f);
    }
    __syncthreads();

    // ---- fc3 (84->10) ----
    if (t < 20) {
        const int o = t >> 1, q = t & 1;
        const float4* wr = (const float4*)(f3w + (size_t)o * 84);
        const float* x0 = f2f + (4 * q) * 88;
        float a0 = f3b[o], a1v = a0, a2 = a0, a3 = a0;
        #pragma unroll
        for (int k = 0; k < 21; ++k) {
            const float4 w4 = wr[k];
            const float4 xa = ((const float4*)x0)[k];
            const float4 xb = ((const float4*)(x0 + 88))[k];
            const float4 xc = ((const float4*)(x0 + 176))[k];
            const float4 xd = ((const float4*)(x0 + 264))[k];
            a0  += w4.x * xa.x + w4.y * xa.y + w4.z * xa.z + w4.w * xa.w;
            a1v += w4.x * xb.x + w4.y * xb.y + w4.z * xb.z + w4.w * xb.w;
            a2  += w4.x * xc.x + w4.y * xc.y + w4.z * xc.z + w4.w * xc.w;
            a3  += w4.x * xd.x + w4.y * xd.y + w4.z * xd.z + w4.w * xd.w;
        }
        lgf[(4 * q + 0) * 12 + o] = a0;
        lgf[(4 * q + 1) * 12 + o] = a1v;
        lgf[(4 * q + 2) * 12 + o] = a2;
        lgf[(4 * q + 3) * 12 + o] = a3;
    }
    __syncthreads();

    // ---- log_softmax per image ----
    if (t < 8) {
        float* lp = lgf + t * 12;
        float mx = -INFINITY;
        #pragma unroll
        for (int i = 0; i < 10; ++i) mx = fmaxf(mx, lp[i]);
        float sum = 0.f;
        #pragma unroll
        for (int i = 0; i < 10; ++i) sum += expf(lp[i] - mx);
        const float lse = mx + logf(sum);
        #pragma unroll
        for (int i = 0; i < 10; ++i) lp[i] -= lse;
    }
    __syncthreads();

    // ---- per-number log-probs (2 batch elements) ----
    for (int idx = t; idx < 400; idx += 256) {
        const int be = idx / 200, r = idx % 200;
        const float* lp = lgf + 4 * be * 12;
        if (r < 100) l1f[be * 100 + r] = lp[r / 10] + lp[12 + r % 10];
        else { const int k = r - 100; l2f[be * 100 + k] = lp[24 + k / 10] + lp[36 + k % 10]; }
    }
    __syncthreads();

    // ---- per-segment exact logsumexp ----
    for (int idx = t; idx < 2 * SUMS; idx += 256) {
        const int be = idx / SUMS, s = idx % SUMS;
        const float* L1 = l1f + be * 100;
        const float* L2 = l2f + be * 100;
        const int ilo = (s > 99) ? (s - 99) : 0;
        const int ihi = (s < 99) ? s : 99;
        float m = -INFINITY;
        for (int i = ilo; i <= ihi; ++i) m = fmaxf(m, L1[i] + L2[s - i]);
        float sum = 0.f;
        for (int i = ilo; i <= ihi; ++i) sum += expf(L1[i] + L2[s - i] - m);
        out[((size_t)bid * 2 + be) * SUMS + s] = logf(sum) + m;
    }
}

extern "C" void kernel_launch(void* const* d_in, const int* in_sizes, int n_in,
                              void* d_out, int out_size, void* d_ws, size_t ws_size,
                              hipStream_t stream) {
    const float* images = (const float*)d_in[0];
    const float* c1w = (const float*)d_in[1];
    const float* c1b = (const float*)d_in[2];
    const float* c2w = (const float*)d_in[3];
    const float* c2b = (const float*)d_in[4];
    const float* f1w = (const float*)d_in[5];
    const float* f1b = (const float*)d_in[6];
    const float* f2w = (const float*)d_in[7];
    const float* f2b = (const float*)d_in[8];
    const float* f3w = (const float*)d_in[9];
    const float* f3b = (const float*)d_in[10];
    float* out = (float*)d_out;

    lenet_circuit_kernel<<<NBLK, 256, 0, stream>>>(
        images, c1w, c1b, c2w, c2b, f1w, f1b, f2w, f2b, f3w, f3b, out);
}

// Round 7
// 198.258 us; speedup vs baseline: 1.9787x; 1.3078x over previous
//
#include <hip/hip_runtime.h>
#include <hip/hip_bf16.h>
#include <math.h>

#define NUMS 100
#define SUMS 199
#define NBLK 2048   // 8 images = 2 batch elements per block

typedef __attribute__((ext_vector_type(8))) short short8;   // 8 bf16
typedef __attribute__((ext_vector_type(4))) float float4v;  // MFMA acc

union Frag8 { short8 v; unsigned u[4]; uint4 q; };

static __device__ inline unsigned pk_bf16(float a, float b) {
    __hip_bfloat162 h = __float22bfloat162_rn(make_float2(a, b));
    union { __hip_bfloat162 h; unsigned u; } c; c.h = h; return c.u;
}

// LDS (31264 B -> 5 blocks/CU):
//  region A [0,12576): images bf16 [8][393 dwords]; after conv1 reused for
//    p2f[8][260] fp32, f1f[8][124], then f2f[8][88], lgf[8][12], e1f/e2f[2][100]
//  p1 [12576,31264): conv1 out bf16 [8 img][12 y][12 x][8 ic-pad] + tail pad.
//  p1 FULLY ZEROED at staging (conv2 uint4 A-loads cover zero-weight pad
//  lanes; stale Inf/NaN there -> 0*Inf=NaN laundered by relu — the R5 bug).
__global__ __launch_bounds__(256) void lenet_circuit_kernel(
    const float* __restrict__ images,
    const float* __restrict__ c1w, const float* __restrict__ c1b,
    const float* __restrict__ c2w, const float* __restrict__ c2b,
    const float* __restrict__ f1w, const float* __restrict__ f1b,
    const float* __restrict__ f2w, const float* __restrict__ f2b,
    const float* __restrict__ f3w, const float* __restrict__ f3b,
    float* __restrict__ out)
{
    __shared__ __align__(16) unsigned char s_mem[31264];
    unsigned*       imgu = (unsigned*)s_mem;                       // [8][393]
    unsigned short* p1s  = (unsigned short*)(s_mem + 12576);       // [8][1152]
    const uint4*    p1u4 = (const uint4*)(s_mem + 12576);
    float*          Af   = (float*)s_mem;

    float* p2f = Af;            // [8][260]
    float* f1f = Af + 2080;     // [8][124]
    float* f2f = Af;            // [8][88]
    float* lgf = Af + 704;      // [8][12]
    float* e1f = Af + 800;      // [2][100]  exp(lp1)
    float* e2f = Af + 1000;     // [2][100]  exp(lp2)

    const int t = threadIdx.x, bid = blockIdx.x;
    const int lane = t & 63, wav = t >> 6;
    const int c = lane & 15, h = lane >> 4;

    // ---- zero the whole p1 region (pads included) ----
    {
        uint4* pz = (uint4*)(s_mem + 12576);
        const uint4 z = {0u, 0u, 0u, 0u};
        for (int i = t; i < 1168; i += 256) pz[i] = z;
    }

    // ---- stage 8 images fp32 -> bf16 packed ----
    {
        const float4* g = (const float4*)(images + (size_t)bid * 6272);
        for (int i = t; i < 1568; i += 256) {
            const float4 v = g[i];
            const int im = i / 196, j = i % 196;
            imgu[im * 393 + 2 * j]     = pk_bf16(v.x, v.y);
            imgu[im * 393 + 2 * j + 1] = pk_bf16(v.z, v.w);
        }
    }

    // ---- conv1 weights (A-side): row = 2*oc + xshift (xshift: w shifted +1 in x) ----
    // K pair p = h*4 + j/2 (p<15): ky = p/3, kxb = 2*(p%3) + (j&1); kx = kxb - xs
    Frag8 a1;
    {
        const int oc = c >> 1, xs = c & 1;
        float v[8];
        #pragma unroll
        for (int j = 0; j < 8; ++j) {
            const int p = h * 4 + (j >> 1);
            float w = 0.f;
            if (p < 15 && c < 12) {
                const int ky = p / 3, kx = 2 * (p % 3) + (j & 1) - xs;
                if (kx >= 0 && kx < 5) w = c1w[oc * 25 + ky * 5 + kx];
            }
            v[j] = w;
        }
        #pragma unroll
        for (int q = 0; q < 4; ++q) a1.u[q] = pk_bf16(v[2 * q], v[2 * q + 1]);
    }

    // ---- conv2 weights (B-side): lane n=c=oc holds k=32s+8h+j; K order (ky,kx6,ic8) ----
    Frag8 w2[8];
    #pragma unroll
    for (int s = 0; s < 8; ++s) {
        float v[8];
        #pragma unroll
        for (int jp = 0; jp < 4; ++jp) {
            const int D = 16 * s + 4 * h + jp;
            const int ky = D / 24, rem = D % 24, kx = rem >> 2, icp = rem & 3;
            const bool ok = (ky < 5 && kx < 5);
            v[2 * jp]     = (ok && 2 * icp < 6)     ? c2w[c * 150 + (2 * icp) * 25 + ky * 5 + kx]     : 0.f;
            v[2 * jp + 1] = (ok && 2 * icp + 1 < 6) ? c2w[c * 150 + (2 * icp + 1) * 25 + ky * 5 + kx] : 0.f;
        }
        #pragma unroll
        for (int q = 0; q < 4; ++q) w2[s].u[q] = pk_bf16(v[2 * q], v[2 * q + 1]);
    }
    int koff[8];   // conv2 A-read offset per K-block, uint4 units
    #pragma unroll
    for (int s = 0; s < 8; ++s) {
        const int D0 = 16 * s + 4 * h;
        koff[s] = (D0 / 24) * 12 + ((D0 % 24) >> 2);
    }
    float bias0 = 0.f, bias1 = 0.f;
    if (h < 3) { bias0 = c1b[2 * h]; bias1 = c1b[2 * h + 1]; }
    __syncthreads();

    // ---- conv1: 1 MFMA per pool-quad; cols n=(y-lsb,img); rows=(oc,x-shift) in-lane pool ----
    {
        int pd[4];
        #pragma unroll
        for (int q = 0; q < 4; ++q) {
            const int p = 4 * h + q;
            pd[q] = (p < 15) ? (p / 3) * 14 + (p % 3) : 0;
        }
        const int n = c, img = n >> 1;
        const int imb = img * 393 + (n & 1) * 14;
        for (int qy = wav * 3; qy < wav * 3 + 3; ++qy) {
            #pragma unroll
            for (int qx = 0; qx < 12; ++qx) {
                const int base = imb + qy * 28 + qx;
                Frag8 bf;
                #pragma unroll
                for (int q = 0; q < 4; ++q) bf.u[q] = imgu[base + pd[q]];
                float4v acc = {0.f, 0.f, 0.f, 0.f};
                acc = __builtin_amdgcn_mfma_f32_16x16x32_bf16(a1.v, bf.v, acc, 0, 0, 0);
                // rows h*4+r = 2*oc+xs: acc[0],acc[1] -> oc=2h; acc[2],acc[3] -> oc=2h+1
                float v0 = fmaxf(acc[0], acc[1]);
                float v1 = fmaxf(acc[2], acc[3]);
                v0 = fmaxf(v0, __shfl_xor(v0, 1));   // y partner (col bit0)
                v1 = fmaxf(v1, __shfl_xor(v1, 1));
                if ((n & 1) == 0 && h < 3) {
                    const unsigned pkv = pk_bf16(fmaxf(v0 + bias0, 0.f),
                                                 fmaxf(v1 + bias1, 0.f));
                    *(unsigned*)&p1s[img * 1152 + qy * 96 + qx * 8 + 2 * h] = pkv;
                }
            }
        }
    }
    __syncthreads();

    // ---- conv2: A = patches (1 ds_read_b128/MFMA), B = weights in regs; in-lane pooling ----
    {
        const int pxl = (c & 1) + 2 * ((c >> 2) & 1);
        const int pyl = ((c >> 1) & 1) + 2 * ((c >> 3) & 1);
        const float b2v = c2b[c];
        #pragma unroll
        for (int ii = 0; ii < 2; ++ii) {
            const int i0 = 2 * wav + ii;
            #pragma unroll
            for (int mt = 0; mt < 4; ++mt) {
                const int px = pxl + 4 * (mt & 1), py = pyl + 4 * (mt >> 1);
                const int base = i0 * 144 + py * 12 + px;
                float4v acc = {0.f, 0.f, 0.f, 0.f};
                #pragma unroll
                for (int s = 0; s < 8; ++s) {
                    Frag8 af; af.q = p1u4[base + koff[s]];
                    acc = __builtin_amdgcn_mfma_f32_16x16x32_bf16(af.v, w2[s].v, acc, 0, 0, 0);
                }
                const float p = fmaxf(fmaxf(acc[0], acc[1]), fmaxf(acc[2], acc[3]));
                const int qx = (h & 1) + 2 * (mt & 1), qy = (h >> 1) + 2 * (mt >> 1);
                p2f[i0 * 260 + c * 16 + qy * 4 + qx] = fmaxf(p + b2v, 0.f);
            }
        }
    }
    __syncthreads();

    // ---- fc1 (256->120)+relu: thread = (o, 4-img group), 1 pass, 4-way ILP ----
    if (t < 240) {
        const int o = t >> 1, q = t & 1;
        const float4* wr = (const float4*)(f1w + (size_t)o * 256);
        const float* x0 = p2f + (4 * q) * 260;
        float a0 = f1b[o], a1v = a0, a2 = a0, a3 = a0;
        #pragma unroll 2
        for (int k = 0; k < 64; ++k) {
            const float4 w4 = wr[k];
            const float4 xa = ((const float4*)x0)[k];
            const float4 xb = ((const float4*)(x0 + 260))[k];
            const float4 xc = ((const float4*)(x0 + 520))[k];
            const float4 xd = ((const float4*)(x0 + 780))[k];
            a0  += w4.x * xa.x + w4.y * xa.y + w4.z * xa.z + w4.w * xa.w;
            a1v += w4.x * xb.x + w4.y * xb.y + w4.z * xb.z + w4.w * xb.w;
            a2  += w4.x * xc.x + w4.y * xc.y + w4.z * xc.z + w4.w * xc.w;
            a3  += w4.x * xd.x + w4.y * xd.y + w4.z * xd.z + w4.w * xd.w;
        }
        f1f[(4 * q + 0) * 124 + o] = fmaxf(a0, 0.f);
        f1f[(4 * q + 1) * 124 + o] = fmaxf(a1v, 0.f);
        f1f[(4 * q + 2) * 124 + o] = fmaxf(a2, 0.f);
        f1f[(4 * q + 3) * 124 + o] = fmaxf(a3, 0.f);
    }
    __syncthreads();

    // ---- fc2 (120->84)+relu ----
    if (t < 168) {
        const int o = t >> 1, q = t & 1;
        const float4* wr = (const float4*)(f2w + (size_t)o * 120);
        const float* x0 = f1f + (4 * q) * 124;
        float a0 = f2b[o], a1v = a0, a2 = a0, a3 = a0;
        #pragma unroll 2
        for (int k = 0; k < 30; ++k) {
            const float4 w4 = wr[k];
            const float4 xa = ((const float4*)x0)[k];
            const float4 xb = ((const float4*)(x0 + 124))[k];
            const float4 xc = ((const float4*)(x0 + 248))[k];
            const float4 xd = ((const float4*)(x0 + 372))[k];
            a0  += w4.x * xa.x + w4.y * xa.y + w4.z * xa.z + w4.w * xa.w;
            a1v += w4.x * xb.x + w4.y * xb.y + w4.z * xb.z + w4.w * xb.w;
            a2  += w4.x * xc.x + w4.y * xc.y + w4.z * xc.z + w4.w * xc.w;
            a3  += w4.x * xd.x + w4.y * xd.y + w4.z * xd.z + w4.w * xd.w;
        }
        f2f[(4 * q + 0) * 88 + o] = fmaxf(a0, 0.f);
        f2f[(4 * q + 1) * 88 + o] = fmaxf(a1v, 0.f);
        f2f[(4 * q + 2) * 88 + o] = fmaxf(a2, 0.f);
        f2f[(4 * q + 3) * 88 + o] = fmaxf(a3, 0.f);
    }
    __syncthreads();

    // ---- fc3 (84->10) ----
    if (t < 20) {
        const int o = t >> 1, q = t & 1;
        const float4* wr = (const float4*)(f3w + (size_t)o * 84);
        const float* x0 = f2f + (4 * q) * 88;
        float a0 = f3b[o], a1v = a0, a2 = a0, a3 = a0;
        #pragma unroll
        for (int k = 0; k < 21; ++k) {
            const float4 w4 = wr[k];
            const float4 xa = ((const float4*)x0)[k];
            const float4 xb = ((const float4*)(x0 + 88))[k];
            const float4 xc = ((const float4*)(x0 + 176))[k];
            const float4 xd = ((const float4*)(x0 + 264))[k];
            a0  += w4.x * xa.x + w4.y * xa.y + w4.z * xa.z + w4.w * xa.w;
            a1v += w4.x * xb.x + w4.y * xb.y + w4.z * xb.z + w4.w * xb.w;
            a2  += w4.x * xc.x + w4.y * xc.y + w4.z * xc.z + w4.w * xc.w;
            a3  += w4.x * xd.x + w4.y * xd.y + w4.z * xd.z + w4.w * xd.w;
        }
        lgf[(4 * q + 0) * 12 + o] = a0;
        lgf[(4 * q + 1) * 12 + o] = a1v;
        lgf[(4 * q + 2) * 12 + o] = a2;
        lgf[(4 * q + 3) * 12 + o] = a3;
    }
    __syncthreads();

    // ---- log_softmax per image ----
    if (t < 8) {
        float* lp = lgf + t * 12;
        float mx = -INFINITY;
        #pragma unroll
        for (int i = 0; i < 10; ++i) mx = fmaxf(mx, lp[i]);
        float sum = 0.f;
        #pragma unroll
        for (int i = 0; i < 10; ++i) sum += expf(lp[i] - mx);
        const float lse = mx + logf(sum);
        #pragma unroll
        for (int i = 0; i < 10; ++i) lp[i] -= lse;
    }
    __syncthreads();

    // ---- per-number PROBS (linear domain; lp<=0 and >~-40 so exp is safe) ----
    for (int idx = t; idx < 400; idx += 256) {
        const int be = idx / 200, r = idx % 200;
        const float* lp = lgf + 4 * be * 12;
        if (r < 100) e1f[be * 100 + r] = expf(lp[r / 10] + lp[12 + r % 10]);
        else { const int k = r - 100; e2f[be * 100 + k] = expf(lp[24 + k / 10] + lp[36 + k % 10]); }
    }
    __syncthreads();

    // ---- per-segment: linear-domain convolution + single log ----
    // Exact in exact arithmetic (segment-max shift cancels); fp32 products
    // >= ~4e-18 >> min normal, so no underflow of any significant term.
    for (int idx = t; idx < 2 * SUMS; idx += 256) {
        const int be = idx / SUMS, s = idx % SUMS;
        const float* E1 = e1f + be * 100;
        const float* E2 = e2f + be * 100;
        const int ilo = (s > 99) ? (s - 99) : 0;
        const int ihi = (s < 99) ? s : 99;
        float sum = 0.f;
        for (int i = ilo; i <= ihi; ++i) sum += E1[i] * E2[s - i];
        out[((size_t)bid * 2 + be) * SUMS + s] = logf(sum);
    }
}

extern "C" void kernel_launch(void* const* d_in, const int* in_sizes, int n_in,
                              void* d_out, int out_size, void* d_ws, size_t ws_size,
                              hipStream_t stream) {
    const float* images = (const float*)d_in[0];
    const float* c1w = (const float*)d_in[1];
    const float* c1b = (const float*)d_in[2];
    const float* c2w = (const float*)d_in[3];
    const float* c2b = (const float*)d_in[4];
    const float* f1w = (const float*)d_in[5];
    const float* f1b = (const float*)d_in[6];
    const float* f2w = (const float*)d_in[7];
    const float* f2b = (const float*)d_in[8];
    const float* f3w = (const float*)d_in[9];
    const float* f3b = (const float*)d_in[10];
    float* out = (float*)d_out;

    lenet_circuit_kernel<<<NBLK, 256, 0, stream>>>(
        images, c1w, c1b, c2w, c2b, f1w, f1b, f2w, f2b, f3w, f3b, out);
}

// Round 8
// 179.257 us; speedup vs baseline: 2.1885x; 1.1060x over previous
//
#include <hip/hip_runtime.h>
#include <hip/hip_bf16.h>
#include <math.h>

#define NUMS 100
#define SUMS 199
#define NBLK 2048   // 8 images = 2 batch elements per block

typedef __attribute__((ext_vector_type(8))) short short8;   // 8 bf16
typedef __attribute__((ext_vector_type(4))) float float4v;  // MFMA acc

union Frag8 { short8 v; unsigned u[4]; uint4 q; };

static __device__ inline unsigned pk_bf16(float a, float b) {
    __hip_bfloat162 h = __float22bfloat162_rn(make_float2(a, b));
    union { __hip_bfloat162 h; unsigned u; } c; c.h = h; return c.u;
}

// ---- pre-kernel: convert FC weights to bf16 B-fragments in d_ws ----
// frag f holds, for lane l: 8 bf16 of W[o=16*nt+(l&15)][k=32*s+8*(l>>4)+j].
// fc1: f in [0,4096)    nt=f>>9, s=(f>>6)&7, l=f&63   (O=120,K=256)
// fc2: f in [4096,5632) nt=.>>8, s=(.>>6)&3, l        (O=84, K=120->128)
// fc3: f in [5632,5824) nt=0,    s=.>>6,     l        (O=10, K=84->96)
__global__ __launch_bounds__(256) void convert_fc_weights(
    const float* __restrict__ f1w, const float* __restrict__ f2w,
    const float* __restrict__ f3w, uint4* __restrict__ ws)
{
    const int g = blockIdx.x * 256 + threadIdx.x;
    if (g >= 5824) return;
    const float* W; int O, K, ld, nt, s, l;
    if (g < 4096)      { W = f1w; O = 120; K = 256; ld = 256; nt = g >> 9; s = (g >> 6) & 7; l = g & 63; }
    else if (g < 5632) { const int f = g - 4096; W = f2w; O = 84; K = 120; ld = 120; nt = f >> 8; s = (f >> 6) & 3; l = f & 63; }
    else               { const int f = g - 5632; W = f3w; O = 10; K = 84;  ld = 84;  nt = 0; s = f >> 6; l = f & 63; }
    const int o = nt * 16 + (l & 15);
    float v[8];
    #pragma unroll
    for (int j = 0; j < 8; ++j) {
        const int k = 32 * s + 8 * (l >> 4) + j;
        v[j] = (o < O && k < K) ? W[o * ld + k] : 0.f;
    }
    uint4 r;
    r.x = pk_bf16(v[0], v[1]); r.y = pk_bf16(v[2], v[3]);
    r.z = pk_bf16(v[4], v[5]); r.w = pk_bf16(v[6], v[7]);
    ws[g] = r;
}

// LDS map (31264 B -> 5 blocks/CU):
//  [0,12576)      images bf16 [8][393 dw]; after conv1 dead ->
//                 A1 bf16 [16 img][256 k] rows padded to 132 dw (8448 B)
//  [12576,31264)  p1 bf16 [8][12][12][8 ic-pad]; after conv2 dead ->
//                 A2 [16][128k] rows pad 68 dw @12576 (4352 B)
//                 A3 [16][96k]  rows pad 52 dw @16928 (3328 B)
//                 lgf [8][12] f32 @20256; e1f/e2f [2][100] @20640/@21440
//  All MFMA-visible pad cells explicitly zeroed (R5 lesson: 0*garbage-Inf
//  = NaN, laundered by relu fmax).
__global__ __launch_bounds__(256) void lenet_circuit_kernel(
    const float* __restrict__ images,
    const float* __restrict__ c1w, const float* __restrict__ c1b,
    const float* __restrict__ c2w, const float* __restrict__ c2b,
    const float* __restrict__ f1b, const float* __restrict__ f2b,
    const float* __restrict__ f3b, const uint4* __restrict__ wsb,
    float* __restrict__ out)
{
    __shared__ __align__(16) unsigned char s_mem[31264];
    unsigned*       imgu = (unsigned*)s_mem;                       // [8][393]
    unsigned short* p1s  = (unsigned short*)(s_mem + 12576);       // [8][1152]
    const uint4*    p1u4 = (const uint4*)(s_mem + 12576);

    const int t = threadIdx.x, bid = blockIdx.x;
    const int lane = t & 63, wav = t >> 6;
    const int c = lane & 15, h = lane >> 4;
    const uint4 z4 = {0u, 0u, 0u, 0u};

    // ---- zero p1 region (conv2 reads zero-weight pad lanes) ----
    {
        uint4* pz = (uint4*)(s_mem + 12576);
        for (int i = t; i < 1168; i += 256) pz[i] = z4;
    }
    // ---- stage 8 images fp32 -> bf16 packed ----
    {
        const float4* g = (const float4*)(images + (size_t)bid * 6272);
        for (int i = t; i < 1568; i += 256) {
            const float4 v = g[i];
            const int im = i / 196, j = i % 196;
            imgu[im * 393 + 2 * j]     = pk_bf16(v.x, v.y);
            imgu[im * 393 + 2 * j + 1] = pk_bf16(v.z, v.w);
        }
    }

    // ---- conv1 weights (A-side): row = 2*oc + xshift ----
    Frag8 a1;
    {
        const int oc = c >> 1, xs = c & 1;
        float v[8];
        #pragma unroll
        for (int j = 0; j < 8; ++j) {
            const int p = h * 4 + (j >> 1);
            float w = 0.f;
            if (p < 15 && c < 12) {
                const int ky = p / 3, kx = 2 * (p % 3) + (j & 1) - xs;
                if (kx >= 0 && kx < 5) w = c1w[oc * 25 + ky * 5 + kx];
            }
            v[j] = w;
        }
        #pragma unroll
        for (int q = 0; q < 4; ++q) a1.u[q] = pk_bf16(v[2 * q], v[2 * q + 1]);
    }
    // ---- conv2 weights (B-side), K order (ky,kx6,ic8) ----
    Frag8 w2[8];
    #pragma unroll
    for (int s = 0; s < 8; ++s) {
        float v[8];
        #pragma unroll
        for (int jp = 0; jp < 4; ++jp) {
            const int D = 16 * s + 4 * h + jp;
            const int ky = D / 24, rem = D % 24, kx = rem >> 2, icp = rem & 3;
            const bool ok = (ky < 5 && kx < 5);
            v[2 * jp]     = (ok && 2 * icp < 6)     ? c2w[c * 150 + (2 * icp) * 25 + ky * 5 + kx]     : 0.f;
            v[2 * jp + 1] = (ok && 2 * icp + 1 < 6) ? c2w[c * 150 + (2 * icp + 1) * 25 + ky * 5 + kx] : 0.f;
        }
        #pragma unroll
        for (int q = 0; q < 4; ++q) w2[s].u[q] = pk_bf16(v[2 * q], v[2 * q + 1]);
    }
    int koff[8];
    #pragma unroll
    for (int s = 0; s < 8; ++s) {
        const int D0 = 16 * s + 4 * h;
        koff[s] = (D0 / 24) * 12 + ((D0 % 24) >> 2);
    }
    float bias0 = 0.f, bias1 = 0.f;
    if (h < 3) { bias0 = c1b[2 * h]; bias1 = c1b[2 * h + 1]; }
    __syncthreads();

    // ---- conv1: 1 MFMA per pool-quad; in-lane x-pool, shfl y-pool ----
    {
        int pd[4];
        #pragma unroll
        for (int q = 0; q < 4; ++q) {
            const int p = 4 * h + q;
            pd[q] = (p < 15) ? (p / 3) * 14 + (p % 3) : 0;
        }
        const int n = c, img = n >> 1;
        const int imb = img * 393 + (n & 1) * 14;
        for (int qy = wav * 3; qy < wav * 3 + 3; ++qy) {
            #pragma unroll
            for (int qx = 0; qx < 12; ++qx) {
                const int base = imb + qy * 28 + qx;
                Frag8 bf;
                #pragma unroll
                for (int q = 0; q < 4; ++q) bf.u[q] = imgu[base + pd[q]];
                float4v acc = {0.f, 0.f, 0.f, 0.f};
                acc = __builtin_amdgcn_mfma_f32_16x16x32_bf16(a1.v, bf.v, acc, 0, 0, 0);
                float v0 = fmaxf(acc[0], acc[1]);
                float v1 = fmaxf(acc[2], acc[3]);
                v0 = fmaxf(v0, __shfl_xor(v0, 1));
                v1 = fmaxf(v1, __shfl_xor(v1, 1));
                if ((n & 1) == 0 && h < 3) {
                    const unsigned pkv = pk_bf16(fmaxf(v0 + bias0, 0.f),
                                                 fmaxf(v1 + bias1, 0.f));
                    *(unsigned*)&p1s[img * 1152 + qy * 96 + qx * 8 + 2 * h] = pkv;
                }
            }
        }
    }
    __syncthreads();

    // ---- conv2: epilogue writes A1 bf16 [16 img][256 k] (rows 8-15 zeroed) ----
    {
        {   // zero A1 rows 8-15 (bytes [4224,8448))
            uint4* az = (uint4*)(s_mem + 4224);
            for (int i = t; i < 264; i += 256) az[i] = z4;
        }
        unsigned* A1d = (unsigned*)s_mem;
        const int pxl = (c & 1) + 2 * ((c >> 2) & 1);
        const int pyl = ((c >> 1) & 1) + 2 * ((c >> 3) & 1);
        const float b2v = c2b[c];
        #pragma unroll
        for (int ii = 0; ii < 2; ++ii) {
            const int i0 = 2 * wav + ii;
            #pragma unroll
            for (int mt = 0; mt < 4; ++mt) {
                const int px = pxl + 4 * (mt & 1), py = pyl + 4 * (mt >> 1);
                const int base = i0 * 144 + py * 12 + px;
                float4v acc = {0.f, 0.f, 0.f, 0.f};
                #pragma unroll
                for (int s = 0; s < 8; ++s) {
                    Frag8 af; af.q = p1u4[base + koff[s]];
                    acc = __builtin_amdgcn_mfma_f32_16x16x32_bf16(af.v, w2[s].v, acc, 0, 0, 0);
                }
                const float p = fmaxf(fmaxf(acc[0], acc[1]), fmaxf(acc[2], acc[3]));
                float v = fmaxf(p + b2v, 0.f);
                const float vp = __shfl_xor(v, 16);   // qx partner lives at h^1
                if ((h & 1) == 0) {
                    const int qy = (h >> 1) + 2 * (mt >> 1);
                    A1d[i0 * 132 + c * 8 + qy * 2 + (mt & 1)] = pk_bf16(v, vp);
                }
            }
        }
    }
    __syncthreads();

    // ---- fc1 via MFMA: M=16(8 imgs), K=256, N=32/wave ----
    {
        unsigned* A2d = (unsigned*)(s_mem + 12576);
        // zero A2 pads: rows 8-15 dw 0-63; rows 0-7 dw 60-63 (disjoint from epilogue)
        for (int i = t; i < 544; i += 256) {
            if (i < 512) A2d[((i >> 6) + 8) * 68 + (i & 63)] = 0u;
            else { const int rr = i - 512; A2d[(rr >> 2) * 68 + 60 + (rr & 3)] = 0u; }
        }
        const uint4* A1q = (const uint4*)s_mem;
        float4v acc0 = {0.f, 0.f, 0.f, 0.f}, acc1 = acc0;
        const int nt0 = 2 * wav;
        #pragma unroll
        for (int s = 0; s < 8; ++s) {
            Frag8 af; af.q = A1q[c * 33 + 4 * s + h];
            Frag8 b0; b0.q = wsb[(nt0 * 8 + s) * 64 + lane];
            Frag8 b1; b1.q = wsb[((nt0 + 1) * 8 + s) * 64 + lane];
            acc0 = __builtin_amdgcn_mfma_f32_16x16x32_bf16(af.v, b0.v, acc0, 0, 0, 0);
            acc1 = __builtin_amdgcn_mfma_f32_16x16x32_bf16(af.v, b1.v, acc1, 0, 0, 0);
        }
        #pragma unroll
        for (int ntl = 0; ntl < 2; ++ntl) {
            const int o = 32 * wav + 16 * ntl + c;
            const float bias = (o < 120) ? f1b[o] : 0.f;
            #pragma unroll
            for (int r = 0; r < 4; ++r) {
                float v = fmaxf((ntl ? acc1[r] : acc0[r]) + bias, 0.f);
                const float vp = __shfl_xor(v, 1);    // o partner at c^1
                if ((c & 1) == 0 && h < 2 && o < 120)
                    A2d[(4 * h + r) * 68 + (o >> 1)] = pk_bf16(v, vp);
            }
        }
    }
    __syncthreads();

    // ---- fc2 via MFMA: K=128, N=96 (6 tiles, waves 0-2) ----
    {
        unsigned* A3d = (unsigned*)(s_mem + 16928);
        // zero A3 pads: rows 8-15 dw 0-47; rows 0-7 dw 42-47
        for (int i = t; i < 432; i += 256) {
            if (i < 384) A3d[(i / 48 + 8) * 52 + i % 48] = 0u;
            else { const int rr = i - 384; A3d[(rr / 6) * 52 + 42 + rr % 6] = 0u; }
        }
        if (wav < 3) {
            const uint4* A2q = (const uint4*)(s_mem + 12576);
            float4v acc0 = {0.f, 0.f, 0.f, 0.f}, acc1 = acc0;
            const int nt0 = 2 * wav;
            #pragma unroll
            for (int s = 0; s < 4; ++s) {
                Frag8 af; af.q = A2q[c * 17 + 4 * s + h];
                Frag8 b0; b0.q = wsb[4096 + (nt0 * 4 + s) * 64 + lane];
                Frag8 b1; b1.q = wsb[4096 + ((nt0 + 1) * 4 + s) * 64 + lane];
                acc0 = __builtin_amdgcn_mfma_f32_16x16x32_bf16(af.v, b0.v, acc0, 0, 0, 0);
                acc1 = __builtin_amdgcn_mfma_f32_16x16x32_bf16(af.v, b1.v, acc1, 0, 0, 0);
            }
            #pragma unroll
            for (int ntl = 0; ntl < 2; ++ntl) {
                const int o = 32 * wav + 16 * ntl + c;
                const float bias = (o < 84) ? f2b[o] : 0.f;
                #pragma unroll
                for (int r = 0; r < 4; ++r) {
                    float v = fmaxf((ntl ? acc1[r] : acc0[r]) + bias, 0.f);
                    const float vp = __shfl_xor(v, 1);
                    if ((c & 1) == 0 && h < 2 && o < 84)
                        A3d[(4 * h + r) * 52 + (o >> 1)] = pk_bf16(v, vp);
                }
            }
        }
    }
    __syncthreads();

    float* lgf = (float*)(s_mem + 20256);   // [8][12]
    float* e1f = (float*)(s_mem + 20640);   // [2][100]
    float* e2f = (float*)(s_mem + 21440);   // [2][100]

    // ---- fc3 via MFMA: K=96, N=16 (wave 0) ----
    if (wav == 0) {
        const uint4* A3q = (const uint4*)(s_mem + 16928);
        float4v acc = {0.f, 0.f, 0.f, 0.f};
        #pragma unroll
        for (int s = 0; s < 3; ++s) {
            Frag8 af; af.q = A3q[c * 13 + 4 * s + h];
            Frag8 b; b.q = wsb[5632 + s * 64 + lane];
            acc = __builtin_amdgcn_mfma_f32_16x16x32_bf16(af.v, b.v, acc, 0, 0, 0);
        }
        if (c < 10 && h < 2) {
            const float bias = f3b[c];
            #pragma unroll
            for (int r = 0; r < 4; ++r) lgf[(4 * h + r) * 12 + c] = acc[r] + bias;
        }
    }
    __syncthreads();

    // ---- log_softmax per image ----
    if (t < 8) {
        float* lp = lgf + t * 12;
        float mx = -INFINITY;
        #pragma unroll
        for (int i = 0; i < 10; ++i) mx = fmaxf(mx, lp[i]);
        float sum = 0.f;
        #pragma unroll
        for (int i = 0; i < 10; ++i) sum += expf(lp[i] - mx);
        const float lse = mx + logf(sum);
        #pragma unroll
        for (int i = 0; i < 10; ++i) lp[i] -= lse;
    }
    __syncthreads();

    // ---- per-number probs (linear domain; lp in (-40,0] so exp is safe) ----
    for (int idx = t; idx < 400; idx += 256) {
        const int be = idx / 200, r = idx % 200;
        const float* lp = lgf + 4 * be * 12;
        if (r < 100) e1f[be * 100 + r] = expf(lp[r / 10] + lp[12 + r % 10]);
        else { const int k = r - 100; e2f[be * 100 + k] = expf(lp[24 + k / 10] + lp[36 + k % 10]); }
    }
    __syncthreads();

    // ---- per-segment: linear convolution + single log ----
    for (int idx = t; idx < 2 * SUMS; idx += 256) {
        const int be = idx / SUMS, s = idx % SUMS;
        const float* E1 = e1f + be * 100;
        const float* E2 = e2f + be * 100;
        const int ilo = (s > 99) ? (s - 99) : 0;
        const int ihi = (s < 99) ? s : 99;
        float sum = 0.f;
        for (int i = ilo; i <= ihi; ++i) sum += E1[i] * E2[s - i];
        out[((size_t)bid * 2 + be) * SUMS + s] = logf(sum);
    }
}

extern "C" void kernel_launch(void* const* d_in, const int* in_sizes, int n_in,
                              void* d_out, int out_size, void* d_ws, size_t ws_size,
                              hipStream_t stream) {
    const float* images = (const float*)d_in[0];
    const float* c1w = (const float*)d_in[1];
    const float* c1b = (const float*)d_in[2];
    const float* c2w = (const float*)d_in[3];
    const float* c2b = (const float*)d_in[4];
    const float* f1w = (const float*)d_in[5];
    const float* f1b = (const float*)d_in[6];
    const float* f2w = (const float*)d_in[7];
    const float* f2b = (const float*)d_in[8];
    const float* f3w = (const float*)d_in[9];
    const float* f3b = (const float*)d_in[10];
    float* out = (float*)d_out;

    convert_fc_weights<<<23, 256, 0, stream>>>(f1w, f2w, f3w, (uint4*)d_ws);
    lenet_circuit_kernel<<<NBLK, 256, 0, stream>>>(
        images, c1w, c1b, c2w, c2b, f1b, f2b, f3b, (const uint4*)d_ws, out);
}

// Round 9
// 151.354 us; speedup vs baseline: 2.5919x; 1.1844x over previous
//
#include <hip/hip_runtime.h>
#include <hip/hip_bf16.h>
#include <math.h>

#define SUMS 199
#define NBLK 1024   // 16 images = 4 batch elements per block, 2 conv passes

typedef __attribute__((ext_vector_type(8))) short short8;   // 8 bf16
typedef __attribute__((ext_vector_type(4))) float float4v;  // MFMA acc

union Frag8 { short8 v; unsigned u[4]; uint4 q; };

static __device__ inline unsigned pk_bf16(float a, float b) {
    __hip_bfloat162 h = __float22bfloat162_rn(make_float2(a, b));
    union { __hip_bfloat162 h; unsigned u; } c; c.h = h; return c.u;
}

// ---- pre-kernel: all weight fragments -> d_ws (bf16 B/A-frag layout) ----
// fc1 [0,4096): nt=g>>9, s=(g>>6)&7   (O=120,K=256)
// fc2 [4096,5632): nt=.>>8, s=(.>>6)&3 (O=84,K=120->128)
// fc3 [5632,5824): nt=0, s=.>>6        (O=10,K=84->96)
// conv2 [5824,6336): s=.>>6            (B-side frags, K order (ky,kx6,ic8))
// conv1 [6336,6400):                   (A-side dual x-shift frags)
__global__ __launch_bounds__(256) void convert_weights(
    const float* __restrict__ f1w, const float* __restrict__ f2w,
    const float* __restrict__ f3w, const float* __restrict__ c1w,
    const float* __restrict__ c2w, uint4* __restrict__ ws)
{
    const int g = blockIdx.x * 256 + threadIdx.x;
    if (g >= 6400) return;
    float v[8];
    if (g < 5824) {
        const float* W; int O, K, ld, nt, s, l;
        if (g < 4096)      { W = f1w; O = 120; K = 256; ld = 256; nt = g >> 9; s = (g >> 6) & 7; l = g & 63; }
        else if (g < 5632) { const int f = g - 4096; W = f2w; O = 84; K = 120; ld = 120; nt = f >> 8; s = (f >> 6) & 3; l = f & 63; }
        else               { const int f = g - 5632; W = f3w; O = 10; K = 84;  ld = 84;  nt = 0; s = f >> 6; l = f & 63; }
        const int o = nt * 16 + (l & 15);
        #pragma unroll
        for (int j = 0; j < 8; ++j) {
            const int k = 32 * s + 8 * (l >> 4) + j;
            v[j] = (o < O && k < K) ? W[o * ld + k] : 0.f;
        }
    } else if (g < 6336) {
        const int f = g - 5824, s = f >> 6, l = f & 63;
        const int c = l & 15, h = l >> 4;
        #pragma unroll
        for (int jp = 0; jp < 4; ++jp) {
            const int D = 16 * s + 4 * h + jp;
            const int ky = D / 24, rem = D % 24, kx = rem >> 2, icp = rem & 3;
            const bool ok = (ky < 5 && kx < 5);
            v[2 * jp]     = (ok && 2 * icp < 6)     ? c2w[c * 150 + (2 * icp) * 25 + ky * 5 + kx]     : 0.f;
            v[2 * jp + 1] = (ok && 2 * icp + 1 < 6) ? c2w[c * 150 + (2 * icp + 1) * 25 + ky * 5 + kx] : 0.f;
        }
    } else {
        const int l = (g - 6336) & 63;
        const int c = l & 15, h = l >> 4;
        const int oc = c >> 1, xs = c & 1;
        #pragma unroll
        for (int j = 0; j < 8; ++j) {
            const int p = h * 4 + (j >> 1);
            float w = 0.f;
            if (p < 15 && c < 12) {
                const int ky = p / 3, kx = 2 * (p % 3) + (j & 1) - xs;
                if (kx >= 0 && kx < 5) w = c1w[oc * 25 + ky * 5 + kx];
            }
            v[j] = w;
        }
    }
    uint4 r;
    r.x = pk_bf16(v[0], v[1]); r.y = pk_bf16(v[2], v[3]);
    r.z = pk_bf16(v[4], v[5]); r.w = pk_bf16(v[6], v[7]);
    ws[g] = r;
}

// LDS map (39712 B -> 4 blocks/CU, grid fully resident):
//  [0,12576)      images bf16 [8][393 dw] (per pass); after pass-B conv2:
//                 A2 [16][68dw] @0, A3 [16][52dw] @4352, lgf [16][12]f32 @7680,
//                 e1f [4][100] @8448, e2f [4][100] @10048
//  [12576,31264)  p1 bf16 [8][12][12][8 ic-pad] + tail (per pass); zeroed once
//                 (conv2 reads zero-weight pad lanes; R5 lesson: stale garbage
//                  -> 0*Inf=NaN laundered by relu fmax)
//  [31264,39712)  A1 bf16 [16 img][132 dw] (all 16 rows real)
__global__ __launch_bounds__(256) void lenet_circuit_kernel(
    const float* __restrict__ images,
    const float* __restrict__ c1b, const float* __restrict__ c2b,
    const float* __restrict__ f1b, const float* __restrict__ f2b,
    const float* __restrict__ f3b, const uint4* __restrict__ wsb,
    float* __restrict__ out)
{
    __shared__ __align__(16) unsigned char s_mem[39712];
    unsigned*       imgu = (unsigned*)s_mem;                       // [8][393]
    unsigned short* p1s  = (unsigned short*)(s_mem + 12576);
    const uint4*    p1u4 = (const uint4*)(s_mem + 12576);
    unsigned*       A1d  = (unsigned*)(s_mem + 31264);
    const uint4*    A1q  = (const uint4*)(s_mem + 31264);

    const int t = threadIdx.x, bid = blockIdx.x;
    const int lane = t & 63, wav = t >> 6;
    const int c = lane & 15, h = lane >> 4;
    const uint4 z4 = {0u, 0u, 0u, 0u};

    // ---- zero p1 region once (pads read by conv2 every pass) ----
    {
        uint4* pz = (uint4*)(s_mem + 12576);
        for (int i = t; i < 1168; i += 256) pz[i] = z4;
    }
    // ---- load weight fragments (coalesced, from pre-kernel) ----
    Frag8 a1; a1.q = wsb[6336 + lane];
    Frag8 w2[8];
    #pragma unroll
    for (int s = 0; s < 8; ++s) w2[s].q = wsb[5824 + s * 64 + lane];
    int koff[8];
    #pragma unroll
    for (int s = 0; s < 8; ++s) {
        const int D0 = 16 * s + 4 * h;
        koff[s] = (D0 / 24) * 12 + ((D0 % 24) >> 2);
    }
    int pd[4];
    #pragma unroll
    for (int q = 0; q < 4; ++q) {
        const int p = 4 * h + q;
        pd[q] = (p < 15) ? (p / 3) * 14 + (p % 3) : 0;
    }
    float bias0 = 0.f, bias1 = 0.f;
    if (h < 3) { bias0 = c1b[2 * h]; bias1 = c1b[2 * h + 1]; }
    const float b2v = c2b[c];

    // ================= two conv passes (8 images each) =================
    for (int pass = 0; pass < 2; ++pass) {
        // ---- stage 8 images fp32 -> bf16 packed ----
        {
            const float4* g = (const float4*)(images + (size_t)bid * 12544 + pass * 6272);
            for (int i = t; i < 1568; i += 256) {
                const float4 v = g[i];
                const int im = i / 196, j = i % 196;
                imgu[im * 393 + 2 * j]     = pk_bf16(v.x, v.y);
                imgu[im * 393 + 2 * j + 1] = pk_bf16(v.z, v.w);
            }
        }
        __syncthreads();

        // ---- conv1: 1 MFMA per pool-quad; in-lane x-pool, shfl y-pool ----
        {
            const int n = c, img = n >> 1;
            const int imb = img * 393 + (n & 1) * 14;
            for (int qy = wav * 3; qy < wav * 3 + 3; ++qy) {
                #pragma unroll
                for (int qx = 0; qx < 12; ++qx) {
                    const int base = imb + qy * 28 + qx;
                    Frag8 bf;
                    #pragma unroll
                    for (int q = 0; q < 4; ++q) bf.u[q] = imgu[base + pd[q]];
                    float4v acc = {0.f, 0.f, 0.f, 0.f};
                    acc = __builtin_amdgcn_mfma_f32_16x16x32_bf16(a1.v, bf.v, acc, 0, 0, 0);
                    float v0 = fmaxf(acc[0], acc[1]);
                    float v1 = fmaxf(acc[2], acc[3]);
                    v0 = fmaxf(v0, __shfl_xor(v0, 1));
                    v1 = fmaxf(v1, __shfl_xor(v1, 1));
                    if ((n & 1) == 0 && h < 3) {
                        const unsigned pkv = pk_bf16(fmaxf(v0 + bias0, 0.f),
                                                     fmaxf(v1 + bias1, 0.f));
                        *(unsigned*)&p1s[img * 1152 + qy * 96 + qx * 8 + 2 * h] = pkv;
                    }
                }
            }
        }
        __syncthreads();

        // ---- conv2 -> A1 rows pass*8 + i0 (no barrier needed after: stage-B
        //      touches only imgu; the stage barrier separates p1 read/write) ----
        {
            const int pxl = (c & 1) + 2 * ((c >> 2) & 1);
            const int pyl = ((c >> 1) & 1) + 2 * ((c >> 3) & 1);
            #pragma unroll
            for (int ii = 0; ii < 2; ++ii) {
                const int i0 = 2 * wav + ii;
                #pragma unroll
                for (int mt = 0; mt < 4; ++mt) {
                    const int px = pxl + 4 * (mt & 1), py = pyl + 4 * (mt >> 1);
                    const int base = i0 * 144 + py * 12 + px;
                    float4v acc = {0.f, 0.f, 0.f, 0.f};
                    #pragma unroll
                    for (int s = 0; s < 8; ++s) {
                        Frag8 af; af.q = p1u4[base + koff[s]];
                        acc = __builtin_amdgcn_mfma_f32_16x16x32_bf16(af.v, w2[s].v, acc, 0, 0, 0);
                    }
                    const float p = fmaxf(fmaxf(acc[0], acc[1]), fmaxf(acc[2], acc[3]));
                    float v = fmaxf(p + b2v, 0.f);
                    const float vp = __shfl_xor(v, 16);   // qx partner at h^1
                    if ((h & 1) == 0) {
                        const int qy = (h >> 1) + 2 * (mt >> 1);
                        A1d[(pass * 8 + i0) * 132 + c * 8 + qy * 2 + (mt & 1)] = pk_bf16(v, vp);
                    }
                }
            }
        }
    }
    __syncthreads();   // A1 complete (all 16 rows)

    // ---- fc1 via MFMA: M=16 (all real), K=256, N=32/wave ----
    {
        unsigned* A2d = (unsigned*)s_mem;
        if (t < 64) A2d[(t >> 2) * 68 + 60 + (t & 3)] = 0u;   // k-pad 120-127
        float4v acc0 = {0.f, 0.f, 0.f, 0.f}, acc1 = acc0;
        const int nt0 = 2 * wav;
        #pragma unroll
        for (int s = 0; s < 8; ++s) {
            Frag8 af; af.q = A1q[c * 33 + 4 * s + h];
            Frag8 b0; b0.q = wsb[(nt0 * 8 + s) * 64 + lane];
            Frag8 b1; b1.q = wsb[((nt0 + 1) * 8 + s) * 64 + lane];
            acc0 = __builtin_amdgcn_mfma_f32_16x16x32_bf16(af.v, b0.v, acc0, 0, 0, 0);
            acc1 = __builtin_amdgcn_mfma_f32_16x16x32_bf16(af.v, b1.v, acc1, 0, 0, 0);
        }
        #pragma unroll
        for (int ntl = 0; ntl < 2; ++ntl) {
            const int o = 32 * wav + 16 * ntl + c;
            const float bias = (o < 120) ? f1b[o] : 0.f;
            #pragma unroll
            for (int r = 0; r < 4; ++r) {
                float v = fmaxf((ntl ? acc1[r] : acc0[r]) + bias, 0.f);
                const float vp = __shfl_xor(v, 1);
                if ((c & 1) == 0 && o < 120)
                    A2d[(4 * h + r) * 68 + (o >> 1)] = pk_bf16(v, vp);
            }
        }
    }
    __syncthreads();

    // ---- fc2 via MFMA: K=128, N=96 (waves 0-2) ----
    {
        unsigned* A3d = (unsigned*)(s_mem + 4352);
        if (t < 96) A3d[(t / 6) * 52 + 42 + (t % 6)] = 0u;    // k-pad 84-95
        if (wav < 3) {
            const uint4* A2q = (const uint4*)s_mem;
            float4v acc0 = {0.f, 0.f, 0.f, 0.f}, acc1 = acc0;
            const int nt0 = 2 * wav;
            #pragma unroll
            for (int s = 0; s < 4; ++s) {
                Frag8 af; af.q = A2q[c * 17 + 4 * s + h];
                Frag8 b0; b0.q = wsb[4096 + (nt0 * 4 + s) * 64 + lane];
                Frag8 b1; b1.q = wsb[4096 + ((nt0 + 1) * 4 + s) * 64 + lane];
                acc0 = __builtin_amdgcn_mfma_f32_16x16x32_bf16(af.v, b0.v, acc0, 0, 0, 0);
                acc1 = __builtin_amdgcn_mfma_f32_16x16x32_bf16(af.v, b1.v, acc1, 0, 0, 0);
            }
            #pragma unroll
            for (int ntl = 0; ntl < 2; ++ntl) {
                const int o = 32 * wav + 16 * ntl + c;
                const float bias = (o < 84) ? f2b[o] : 0.f;
                #pragma unroll
                for (int r = 0; r < 4; ++r) {
                    float v = fmaxf((ntl ? acc1[r] : acc0[r]) + bias, 0.f);
                    const float vp = __shfl_xor(v, 1);
                    if ((c & 1) == 0 && o < 84)
                        A3d[(4 * h + r) * 52 + (o >> 1)] = pk_bf16(v, vp);
                }
            }
        }
    }
    __syncthreads();

    float* lgf = (float*)(s_mem + 7680);    // [16][12]
    float* e1f = (float*)(s_mem + 8448);    // [4][100]
    float* e2f = (float*)(s_mem + 10048);   // [4][100]

    // ---- fc3 via MFMA: K=96, N=16 (wave 0), 16 real rows ----
    if (wav == 0) {
        const uint4* A3q = (const uint4*)(s_mem + 4352);
        float4v acc = {0.f, 0.f, 0.f, 0.f};
        #pragma unroll
        for (int s = 0; s < 3; ++s) {
            Frag8 af; af.q = A3q[c * 13 + 4 * s + h];
            Frag8 b; b.q = wsb[5632 + s * 64 + lane];
            acc = __builtin_amdgcn_mfma_f32_16x16x32_bf16(af.v, b.v, acc, 0, 0, 0);
        }
        if (c < 10) {
            const float bias = f3b[c];
            #pragma unroll
            for (int r = 0; r < 4; ++r) lgf[(4 * h + r) * 12 + c] = acc[r] + bias;
        }
    }
    __syncthreads();

    // ---- log_softmax per image (16) ----
    if (t < 16) {
        float* lp = lgf + t * 12;
        float mx = -INFINITY;
        #pragma unroll
        for (int i = 0; i < 10; ++i) mx = fmaxf(mx, lp[i]);
        float sum = 0.f;
        #pragma unroll
        for (int i = 0; i < 10; ++i) sum += expf(lp[i] - mx);
        const float lse = mx + logf(sum);
        #pragma unroll
        for (int i = 0; i < 10; ++i) lp[i] -= lse;
    }
    __syncthreads();

    // ---- per-number probs (linear domain; lp in (-40,0] so exp safe) ----
    for (int idx = t; idx < 800; idx += 256) {
        const int be = idx / 200, r = idx % 200;
        const float* lp = lgf + 4 * be * 12;
        if (r < 100) e1f[be * 100 + r] = expf(lp[r / 10] + lp[12 + r % 10]);
        else { const int k = r - 100; e2f[be * 100 + k] = expf(lp[24 + k / 10] + lp[36 + k % 10]); }
    }
    __syncthreads();

    // ---- segments, pair (sp, sp+99): trips s+1 and 100-s sum to ~101 ----
    for (int pid = t; pid < 400; pid += 256) {
        const int be = pid / 100, sp = pid % 100;
        const float* E1 = e1f + be * 100;
        const float* E2 = e2f + be * 100;
        float* ob = out + ((size_t)bid * 4 + be) * SUMS;
        float s1 = 0.f;
        for (int i = 0; i <= sp; ++i) s1 += E1[i] * E2[sp - i];
        ob[sp] = logf(s1);
        if (sp >= 1) {
            float s2 = 0.f;
            for (int i = sp; i <= 99; ++i) s2 += E1[i] * E2[sp + 99 - i];
            ob[sp + 99] = logf(s2);
        }
    }
}

extern "C" void kernel_launch(void* const* d_in, const int* in_sizes, int n_in,
                              void* d_out, int out_size, void* d_ws, size_t ws_size,
                              hipStream_t stream) {
    const float* images = (const float*)d_in[0];
    const float* c1w = (const float*)d_in[1];
    const float* c1b = (const float*)d_in[2];
    const float* c2w = (const float*)d_in[3];
    const float* c2b = (const float*)d_in[4];
    const float* f1w = (const float*)d_in[5];
    const float* f1b = (const float*)d_in[6];
    const float* f2w = (const float*)d_in[7];
    const float* f2b = (const float*)d_in[8];
    const float* f3w = (const float*)d_in[9];
    const float* f3b = (const float*)d_in[10];
    float* out = (float*)d_out;

    convert_weights<<<25, 256, 0, stream>>>(f1w, f2w, f3w, c1w, c2w, (uint4*)d_ws);
    lenet_circuit_kernel<<<NBLK, 256, 0, stream>>>(
        images, c1b, c2b, f1b, f2b, f3b, (const uint4*)d_ws, out);
}